// Round 7
// baseline (402.663 us; speedup 1.0000x reference)
//
#include <hip/hip_runtime.h>
#include <math.h>

#define B_    32
#define CIN   256
#define HID   256
#define OC    65
#define A_    9
#define H_    56
#define W_    56
#define HW    3136
#define AHW   28224
#define NBOX  64
#define M_    2048
#define CNUM  20
#define NTILE 49         // HW / 64

#define IOU_N ((size_t)B_ * AHW * NBOX)      // 57,802,752
#define X2_BYTES ((size_t)B_ * OC * HW * 4)  // 26,091,520

// padded LDS fragment offset (halfwords): +16B every 8 fragment rows.
#define FOFF(frag) (((frag) << 3) + ((((frag) >> 3)) << 3))

typedef _Float16 half8 __attribute__((ext_vector_type(8)));
typedef float f32x16 __attribute__((ext_vector_type(16)));
typedef float f32x4  __attribute__((ext_vector_type(4)));

__device__ __forceinline__ unsigned int pkh(float a, float b) {
    _Float16 ha = (_Float16)a, hb = (_Float16)b;
    unsigned short ua = __builtin_bit_cast(unsigned short, ha);
    unsigned short ub = __builtin_bit_cast(unsigned short, hb);
    return (unsigned int)ua | ((unsigned int)ub << 16);
}

// Pre-swizzle weights into MFMA A-fragment order (fp16).
__global__ __launch_bounds__(256) void prep_kernel(
    const float* __restrict__ w1, const float* __restrict__ w2,
    _Float16* __restrict__ w1s, _Float16* __restrict__ w2s)
{
    const int f = blockIdx.x * 256 + threadIdx.x;   // 0..65535
    {
        const int e    = f & 7;
        const int lane = (f >> 3) & 63;
        const int kc   = (f >> 9) & 15;
        const int ob   = f >> 13;
        const int row  = ob * 32 + (lane & 31);
        const int k    = kc * 16 + (lane >> 5) * 8 + e;
        w1s[f] = (_Float16)w1[row * CIN + k];
    }
    if (f < 20480) {
        const int e    = f & 7;
        const int lane = (f >> 3) & 63;
        const int ks2  = (f >> 9) & 7;
        const int rt   = f >> 12;
        const int row  = rt * 16 + (lane & 15);
        const int k    = ks2 * 32 + (lane >> 4) * 8 + e;
        w2s[f] = (row < OC) ? (_Float16)w2[row * HID + k] : (_Float16)0.f;
    }
}

// Fused conv1 + conv2 + IoU. Block = (batch, 64-px tile), 4 waves.
// Staging is explicitly load-prefetch-pipelined (2 chunks in flight);
// accumulators initialized after staging to keep VGPR pressure low there.
__global__ __launch_bounds__(256) void conv_iou_kernel(
    const float* __restrict__ features, const _Float16* __restrict__ w1s,
    const float* __restrict__ b1, const _Float16* __restrict__ w2s,
    const float* __restrict__ b2, const float* __restrict__ anc,
    const float* __restrict__ bboxes, float* __restrict__ x2,
    float* __restrict__ iou_out)
{
    __shared__ _Float16 lds_h[18432];   // 36 KB: feat frags -> hidf -> x2tile+prop
    __shared__ float bias_s[HID];       // 1 KB
    __shared__ float boxs[5 * 64];      // 1.25 KB

    _Float16* featAll = lds_h;
    _Float16* hidf    = lds_h;
    float*    L       = (float*)lds_h;
    float*    x2t     = L;              // 64*69 floats
    float*    ppx1    = L + 4416;
    float*    ppy1    = L + 4992;
    float*    ppx2    = L + 5568;
    float*    ppy2    = L + 6144;
    float*    pare    = L + 6720;

    const int t    = threadIdx.x;
    const int lane = t & 63;
    const int w    = t >> 6;
    const int bid  = blockIdx.x;
    const int b    = bid / NTILE;
    const int p0   = (bid - b * NTILE) * 64;
    const float* fbase = features + (size_t)b * CIN * HW + p0;

    bias_s[t] = b1[t];
    if (t < 64) {
        const float* gb = bboxes + ((size_t)b * NBOX + t) * 5;
        const float x1 = gb[0], y1 = gb[1], x2v = gb[2], y2v = gb[3];
        boxs[t] = x1; boxs[64 + t] = y1; boxs[128 + t] = x2v; boxs[192 + t] = y2v;
        boxs[256 + t] = (x2v - x1) * (y2v - y1);
    }

    // staging coords
    const int pstage = (t & 15) * 4;
    const int kk     = (t >> 4) * 2;
    const int ksS    = kk >> 4;
    const int gS     = (kk >> 3) & 1;
    const int j0h    = kk & 7;
    const int ghalf  = lane >> 5;

    // ---- stage ALL 8 feature chunks with a 2-deep load prefetch pipeline ----
    {
        float4 pr0[2], pr1[2];
        pr0[0] = *(const float4*)(fbase + (size_t)kk * HW + pstage);
        pr1[0] = *(const float4*)(fbase + (size_t)(kk + 1) * HW + pstage);
#pragma unroll
        for (int c = 0; c < 8; ++c) {
            if (c < 7) {
                pr0[(c + 1) & 1] = *(const float4*)(fbase + (size_t)((c + 1) * 32 + kk) * HW + pstage);
                pr1[(c + 1) & 1] = *(const float4*)(fbase + (size_t)((c + 1) * 32 + kk + 1) * HW + pstage);
            }
            const float4 r0 = pr0[c & 1];
            const float4 r1 = pr1[c & 1];
            const float a0[4] = {r0.x, r0.y, r0.z, r0.w};
            const float a1[4] = {r1.x, r1.y, r1.z, r1.w};
#pragma unroll
            for (int e = 0; e < 4; ++e) {
                const int p     = pstage + e;
                const int lane2 = gS * 32 + (p & 31);
                const int pt    = p >> 5;
                const int frag  = c * 256 + (ksS * 2 + pt) * 64 + lane2;
                *(unsigned int*)&featAll[FOFF(frag) + j0h] = pkh(a0[e], a1[e]);
            }
        }
    }
    __syncthreads();

    // ---- conv1: wave w -> hidden rows [64w,64w+64), 2x2 32x32x16 accums ----
    f32x16 facc[2][2];
#pragma unroll
    for (int ot = 0; ot < 2; ++ot)
#pragma unroll
        for (int pt = 0; pt < 2; ++pt)
#pragma unroll
            for (int e = 0; e < 16; ++e) facc[ot][pt][e] = 0.f;

    half8 afb[2][2][2];
#pragma unroll
    for (int ks = 0; ks < 2; ++ks)
#pragma unroll
        for (int ot = 0; ot < 2; ++ot)
            afb[0][ks][ot] = *(const half8*)(w1s + ((size_t)((w * 2 + ot) * 16 + ks) * 64 + lane) * 8);

#pragma unroll
    for (int c = 0; c < 8; ++c) {
        if (c < 7) {
#pragma unroll
            for (int ks = 0; ks < 2; ++ks)
#pragma unroll
                for (int ot = 0; ot < 2; ++ot)
                    afb[(c + 1) & 1][ks][ot] =
                        *(const half8*)(w1s + ((size_t)((w * 2 + ot) * 16 + (c + 1) * 2 + ks) * 64 + lane) * 8);
        }
#pragma unroll
        for (int ks = 0; ks < 2; ++ks) {
#pragma unroll
            for (int pt = 0; pt < 2; ++pt) {
                const half8 bf = *(const half8*)&featAll[FOFF(c * 256 + (ks * 2 + pt) * 64 + lane)];
                facc[0][pt] = __builtin_amdgcn_mfma_f32_32x32x16_f16(afb[c & 1][ks][0], bf, facc[0][pt], 0, 0, 0);
                facc[1][pt] = __builtin_amdgcn_mfma_f32_32x32x16_f16(afb[c & 1][ks][1], bf, facc[1][pt], 0, 0, 0);
            }
        }
    }
    __syncthreads();

    // ---- bias + leaky relu, repack to conv2 B-fragment order ----
    const int col = lane & 31;
#pragma unroll
    for (int ot = 0; ot < 2; ++ot) {
        const int ks2 = w * 2 + ot;
#pragma unroll
        for (int pt = 0; pt < 2; ++pt) {
            const int pt2 = pt * 2 + (col >> 4);
            const int n15 = col & 15;
#pragma unroll
            for (int q = 0; q < 4; ++q) {
                float hv[4];
#pragma unroll
                for (int i = 0; i < 4; ++i) {
                    const int row = i + 8 * q + 4 * ghalf;
                    float v = facc[ot][pt][q * 4 + i] + bias_s[w * 64 + ot * 32 + row];
                    hv[i] = v < 0.f ? 0.01f * v : v;
                }
                const int frag = (ks2 * 4 + pt2) * 64 + (q * 16 + n15);
                *(unsigned int*)&hidf[FOFF(frag) + 4 * ghalf]     = pkh(hv[0], hv[1]);
                *(unsigned int*)&hidf[FOFF(frag) + 4 * ghalf + 2] = pkh(hv[2], hv[3]);
            }
        }
    }
    __syncthreads();

    // ---- conv2 via 16x16x32 MFMA; wave w owns pixels [16w,16w+16) ----
    f32x4 c2[5];
#pragma unroll
    for (int rt = 0; rt < 5; ++rt)
#pragma unroll
        for (int e = 0; e < 4; ++e) c2[rt][e] = 0.f;

    const int m16 = lane & 15;
    const int kgr = lane >> 4;
#pragma unroll 2
    for (int ks2 = 0; ks2 < 8; ++ks2) {
        const half8 bf = *(const half8*)&hidf[FOFF((ks2 * 4 + w) * 64 + lane)];
#pragma unroll
        for (int rt = 0; rt < 5; ++rt) {
            const half8 af = *(const half8*)(w2s + ((size_t)(rt * 8 + ks2) * 64 + lane) * 8);
            c2[rt] = __builtin_amdgcn_mfma_f32_16x16x32_f16(af, bf, c2[rt], 0, 0, 0);
        }
    }
    __syncthreads();   // all hidf reads done; alias LDS as x2t/prop

    // ---- write x2 (global, nontemporal) + x2 tile (LDS, for IoU) ----
    float* xb = x2 + (size_t)b * OC * HW + p0 + w * 16 + m16;
    const int pxl = w * 16 + m16;
#pragma unroll
    for (int rt = 0; rt < 5; ++rt) {
#pragma unroll
        for (int r = 0; r < 4; ++r) {
            const int o2 = rt * 16 + kgr * 4 + r;
            const float v = c2[rt][r] + b2[o2];
            if (o2 < OC) {
                __builtin_nontemporal_store(v, xb + (size_t)o2 * HW);
                x2t[pxl * 69 + o2] = v;
            }
        }
    }
    __syncthreads();

    // ---- build 576 proposals (a, px) into LDS ----
    for (int pi = t; pi < A_ * 64; pi += 256) {
        const int a  = pi >> 6;
        const int px = pi & 63;
        const float* xr = x2t + px * 69 + 5 * a;
        const float tx = xr[1], ty = xr[2], tw = xr[3], th = xr[4];
        const int hw = p0 + px;
        const int h  = hw / W_;
        const int wv = hw - h * W_;
        const float gx = (float)wv + 0.5f;
        const float gy = (float)h + 0.5f;
        const float nw = anc[2 * a]     * __expf(tw);
        const float nh = anc[2 * a + 1] * __expf(th);
        const float cx = gx + tx, cy = gy + ty;
        ppx1[pi] = cx - 0.5f * nw; ppy1[pi] = cy - 0.5f * nh;
        ppx2[pi] = cx + 0.5f * nw; ppy2[pi] = cy + 0.5f * nh;
        pare[pi] = nw * nh;
    }
    __syncthreads();

    // ---- IoU stream-out: per (a,q) each wave stores one contiguous 1KB span ----
    const int pr = lane >> 4;
    const int j0 = (lane & 15) * 4;
    float Bx1[4], By1[4], Bx2[4], By2[4], Ba[4];
#pragma unroll
    for (int e = 0; e < 4; ++e) {
        Bx1[e] = boxs[j0 + e];       By1[e] = boxs[64 + j0 + e];
        Bx2[e] = boxs[128 + j0 + e]; By2[e] = boxs[192 + j0 + e];
        Ba[e]  = boxs[256 + j0 + e];
    }
    float* ibase = iou_out + ((size_t)b * AHW + p0) * 64;
#pragma unroll 1
    for (int a = 0; a < A_; ++a) {
#pragma unroll
        for (int q = 0; q < 4; ++q) {
            const int p = w * 16 + q * 4 + pr;
            const int i = a * 64 + p;
            const float Px1 = ppx1[i], Py1 = ppy1[i], Px2 = ppx2[i], Py2 = ppy2[i];
            const float pa = pare[i];
            f32x4 o4;
#pragma unroll
            for (int e = 0; e < 4; ++e) {
                const float iw = fminf(Px2, Bx2[e]) - fmaxf(Px1, Bx1[e]);
                const float ih = fminf(Py2, By2[e]) - fmaxf(Py1, By1[e]);
                const float inter = fmaxf(iw, 0.f) * fmaxf(ih, 0.f);
                o4[e] = inter * __builtin_amdgcn_rcpf(Ba[e] + pa - inter);
            }
            __builtin_nontemporal_store(o4, (f32x4*)(ibase + ((size_t)a * HW + p) * 64 + j0));
        }
    }
}

// blocks 0..159: class_pos gather (256 thr); blocks 160..162: loss partials via atomics-free
// split: block 160 handles loss alone (single block, 256 thr).
__global__ __launch_bounds__(256) void tail_kernel(
    const float* __restrict__ x2, const int* __restrict__ pos_idx,
    const int* __restrict__ neg_idx, const float* __restrict__ gt_off,
    float* __restrict__ cls_out, float* __restrict__ out0)
{
    const int t = threadIdx.x;
    if (blockIdx.x < 160) {
        const int g = blockIdx.x * 256 + t;   // 0..40959
        const int m = g / CNUM;
        const int c = g - m * CNUM;
        const int idx = pos_idx[m];
        const int bi  = idx / AHW;
        const int hw  = idx % HW;
        cls_out[g] = x2[((size_t)bi * OC + 45 + c) * HW + hw];
        return;
    }
    float csum = 0.f, rsum = 0.f;
    for (int m = t; m < M_; m += 256) {
        const int idx = pos_idx[m];
        const int bi = idx / AHW;
        const int rr = idx - bi * AHW;
        const int a  = rr / HW;
        const int hw = rr - a * HW;
        const float* xb = x2 + ((size_t)bi * OC + 5 * a) * HW + hw;
        const float s = 1.f / (1.f + __expf(-xb[0]));
        csum += (s - 1.f) * (s - 1.f);
#pragma unroll
        for (int k = 0; k < 4; ++k) {
            const float d = xb[(size_t)(k + 1) * HW] - gt_off[m * 4 + k];
            rsum += d * d;
        }
    }
    for (int m = t; m < M_; m += 256) {
        const int idx = neg_idx[m];
        const int bi = idx / AHW;
        const int rr = idx - bi * AHW;
        const int a  = rr / HW;
        const int hw = rr - a * HW;
        const float s = 1.f / (1.f + __expf(-x2[((size_t)bi * OC + 5 * a) * HW + hw]));
        csum += s * s;
    }
    __shared__ float red[8];
#pragma unroll
    for (int off = 32; off > 0; off >>= 1) {
        csum += __shfl_down(csum, off, 64);
        rsum += __shfl_down(rsum, off, 64);
    }
    if ((t & 63) == 0) { red[t >> 6] = csum; red[4 + (t >> 6)] = rsum; }
    __syncthreads();
    if (t == 0) {
        const float c = red[0] + red[1] + red[2] + red[3];
        const float rg = red[4] + red[5] + red[6] + red[7];
        out0[0] = c / (2.f * (float)M_) + rg / (float)M_;
    }
}

extern "C" void kernel_launch(void* const* d_in, const int* in_sizes, int n_in,
                              void* d_out, int out_size, void* d_ws, size_t ws_size,
                              hipStream_t stream) {
    (void)in_sizes; (void)n_in; (void)out_size; (void)ws_size;
    const float* features = (const float*)d_in[0];
    const float* w1       = (const float*)d_in[1];
    const float* b1       = (const float*)d_in[2];
    const float* w2       = (const float*)d_in[3];
    const float* b2       = (const float*)d_in[4];
    const float* anc      = (const float*)d_in[5];
    const float* bboxes   = (const float*)d_in[7];
    const float* gt_off   = (const float*)d_in[8];
    const int*   pos_idx  = (const int*)d_in[9];
    const int*   neg_idx  = (const int*)d_in[10];
    float* out = (float*)d_out;

    char* wsb = (char*)d_ws;
    float* x2 = (float*)wsb;                                  // 26,091,520 B
    _Float16* w1s = (_Float16*)(wsb + X2_BYTES);              // 131,072 B
    _Float16* w2s = w1s + 65536;                              // 40,960 B

    prep_kernel<<<256, 256, 0, stream>>>(w1, w2, w1s, w2s);
    conv_iou_kernel<<<B_ * NTILE, 256, 0, stream>>>(features, w1s, b1, w2s, b2,
                                                    anc, bboxes, x2, out + 1);
    tail_kernel<<<161, 256, 0, stream>>>(x2, pos_idx, neg_idx, gt_off, out + 1 + IOU_N, out);
}

// Round 8
// 379.081 us; speedup vs baseline: 1.0622x; 1.0622x over previous
//
#include <hip/hip_runtime.h>
#include <math.h>

#define B_    32
#define CIN   256
#define HID   256
#define OC    65
#define A_    9
#define H_    56
#define W_    56
#define HW    3136
#define AHW   28224
#define NBOX  64
#define M_    2048
#define CNUM  20
#define NTILE 49         // HW / 64

#define IOU_N ((size_t)B_ * AHW * NBOX)      // 57,802,752

// padded LDS fragment offset (halfwords): +16B every 8 fragment rows.
#define FOFF(frag) (((frag) << 3) + ((((frag) >> 3)) << 3))

typedef _Float16 half8 __attribute__((ext_vector_type(8)));
typedef float f32x16 __attribute__((ext_vector_type(16)));
typedef float f32x4  __attribute__((ext_vector_type(4)));

__device__ __forceinline__ unsigned int pkh(float a, float b) {
    _Float16 ha = (_Float16)a, hb = (_Float16)b;
    unsigned short ua = __builtin_bit_cast(unsigned short, ha);
    unsigned short ub = __builtin_bit_cast(unsigned short, hb);
    return (unsigned int)ua | ((unsigned int)ub << 16);
}

// Pre-swizzle weights into MFMA A-fragment order (fp16); zero the loss accumulators.
__global__ __launch_bounds__(256) void prep_kernel(
    const float* __restrict__ w1, const float* __restrict__ w2,
    _Float16* __restrict__ w1s, _Float16* __restrict__ w2s,
    float* __restrict__ loss_ws)
{
    const int f = blockIdx.x * 256 + threadIdx.x;   // 0..65535
    if (f < 2) loss_ws[f] = 0.f;
    {
        const int e    = f & 7;
        const int lane = (f >> 3) & 63;
        const int kc   = (f >> 9) & 15;
        const int ob   = f >> 13;
        const int row  = ob * 32 + (lane & 31);
        const int k    = kc * 16 + (lane >> 5) * 8 + e;
        w1s[f] = (_Float16)w1[row * CIN + k];
    }
    if (f < 20480) {
        const int e    = f & 7;
        const int lane = (f >> 3) & 63;
        const int ks2  = (f >> 9) & 7;
        const int rt   = f >> 12;
        const int row  = rt * 16 + (lane & 15);
        const int k    = ks2 * 32 + (lane >> 4) * 8 + e;
        w2s[f] = (row < OC) ? (_Float16)w2[row * HID + k] : (_Float16)0.f;
    }
}

// Fused conv1 + conv2 + IoU + class-gather + loss-partials.
// Block = (batch, 64-px tile), 4 waves. x2 never touches HBM: the 64x65 tile
// stays in LDS; IoU streams out; pos/neg index scans emit class rows and
// loss terms directly from LDS.
__global__ __launch_bounds__(256) void conv_iou_kernel(
    const float* __restrict__ features, const _Float16* __restrict__ w1s,
    const float* __restrict__ b1, const _Float16* __restrict__ w2s,
    const float* __restrict__ b2, const float* __restrict__ anc,
    const float* __restrict__ bboxes, const int* __restrict__ pos_idx,
    const int* __restrict__ neg_idx, const float* __restrict__ gt_off,
    float* __restrict__ iou_out, float* __restrict__ cls_out,
    float* __restrict__ loss_ws)
{
    __shared__ _Float16 lds_h[18432];   // 36 KB: feat frags -> hidf -> x2tile+prop
    __shared__ float bias_s[HID];       // 1 KB
    __shared__ float boxs[5 * 64];      // 1.25 KB
    __shared__ float red[8];

    _Float16* featAll = lds_h;
    _Float16* hidf    = lds_h;
    float*    L       = (float*)lds_h;
    float*    x2t     = L;              // 64*69 floats (stride-69, conflict-free)
    float*    ppx1    = L + 4416;
    float*    ppy1    = L + 4992;
    float*    ppx2    = L + 5568;
    float*    ppy2    = L + 6144;
    float*    pare    = L + 6720;       // ends 7296 < 9216

    const int t    = threadIdx.x;
    const int lane = t & 63;
    const int w    = t >> 6;
    const int bid  = blockIdx.x;
    const int b    = bid / NTILE;
    const int p0   = (bid - b * NTILE) * 64;
    const float* fbase = features + (size_t)b * CIN * HW + p0;

    bias_s[t] = b1[t];
    if (t < 64) {
        const float* gb = bboxes + ((size_t)b * NBOX + t) * 5;
        const float x1 = gb[0], y1 = gb[1], x2v = gb[2], y2v = gb[3];
        boxs[t] = x1; boxs[64 + t] = y1; boxs[128 + t] = x2v; boxs[192 + t] = y2v;
        boxs[256 + t] = (x2v - x1) * (y2v - y1);
    }

    // staging coords
    const int pstage = (t & 15) * 4;
    const int kk     = (t >> 4) * 2;
    const int ksS    = kk >> 4;
    const int gS     = (kk >> 3) & 1;
    const int j0h    = kk & 7;
    const int ghalf  = lane >> 5;

    // ---- stage ALL 8 feature chunks, fp32->fp16, padded fragment order ----
#pragma unroll
    for (int c = 0; c < 8; ++c) {
        const float4 r0 = *(const float4*)(fbase + (size_t)(c * 32 + kk) * HW + pstage);
        const float4 r1 = *(const float4*)(fbase + (size_t)(c * 32 + kk + 1) * HW + pstage);
        const float a0[4] = {r0.x, r0.y, r0.z, r0.w};
        const float a1[4] = {r1.x, r1.y, r1.z, r1.w};
#pragma unroll
        for (int e = 0; e < 4; ++e) {
            const int p     = pstage + e;
            const int lane2 = gS * 32 + (p & 31);
            const int pt    = p >> 5;
            const int frag  = c * 256 + (ksS * 2 + pt) * 64 + lane2;
            *(unsigned int*)&featAll[FOFF(frag) + j0h] = pkh(a0[e], a1[e]);
        }
    }
    __syncthreads();

    // ---- conv1: wave w -> hidden rows [64w,64w+64), 2x2 32x32x16 accums ----
    f32x16 facc[2][2];
#pragma unroll
    for (int ot = 0; ot < 2; ++ot)
#pragma unroll
        for (int pt = 0; pt < 2; ++pt)
#pragma unroll
            for (int e = 0; e < 16; ++e) facc[ot][pt][e] = 0.f;

    half8 afb[2][2][2];
#pragma unroll
    for (int ks = 0; ks < 2; ++ks)
#pragma unroll
        for (int ot = 0; ot < 2; ++ot)
            afb[0][ks][ot] = *(const half8*)(w1s + ((size_t)((w * 2 + ot) * 16 + ks) * 64 + lane) * 8);

#pragma unroll
    for (int c = 0; c < 8; ++c) {
        if (c < 7) {
#pragma unroll
            for (int ks = 0; ks < 2; ++ks)
#pragma unroll
                for (int ot = 0; ot < 2; ++ot)
                    afb[(c + 1) & 1][ks][ot] =
                        *(const half8*)(w1s + ((size_t)((w * 2 + ot) * 16 + (c + 1) * 2 + ks) * 64 + lane) * 8);
        }
#pragma unroll
        for (int ks = 0; ks < 2; ++ks) {
#pragma unroll
            for (int pt = 0; pt < 2; ++pt) {
                const half8 bf = *(const half8*)&featAll[FOFF(c * 256 + (ks * 2 + pt) * 64 + lane)];
                facc[0][pt] = __builtin_amdgcn_mfma_f32_32x32x16_f16(afb[c & 1][ks][0], bf, facc[0][pt], 0, 0, 0);
                facc[1][pt] = __builtin_amdgcn_mfma_f32_32x32x16_f16(afb[c & 1][ks][1], bf, facc[1][pt], 0, 0, 0);
            }
        }
    }
    __syncthreads();

    // ---- bias + leaky relu, repack to conv2 B-fragment order ----
    const int col = lane & 31;
#pragma unroll
    for (int ot = 0; ot < 2; ++ot) {
        const int ks2 = w * 2 + ot;
#pragma unroll
        for (int pt = 0; pt < 2; ++pt) {
            const int pt2 = pt * 2 + (col >> 4);
            const int n15 = col & 15;
#pragma unroll
            for (int q = 0; q < 4; ++q) {
                float hv[4];
#pragma unroll
                for (int i = 0; i < 4; ++i) {
                    const int row = i + 8 * q + 4 * ghalf;
                    float v = facc[ot][pt][q * 4 + i] + bias_s[w * 64 + ot * 32 + row];
                    hv[i] = v < 0.f ? 0.01f * v : v;
                }
                const int frag = (ks2 * 4 + pt2) * 64 + (q * 16 + n15);
                *(unsigned int*)&hidf[FOFF(frag) + 4 * ghalf]     = pkh(hv[0], hv[1]);
                *(unsigned int*)&hidf[FOFF(frag) + 4 * ghalf + 2] = pkh(hv[2], hv[3]);
            }
        }
    }
    __syncthreads();

    // ---- conv2 via 16x16x32 MFMA; wave w owns pixels [16w,16w+16) ----
    f32x4 c2[5];
#pragma unroll
    for (int rt = 0; rt < 5; ++rt)
#pragma unroll
        for (int e = 0; e < 4; ++e) c2[rt][e] = 0.f;

    const int m16 = lane & 15;
    const int kgr = lane >> 4;
#pragma unroll 2
    for (int ks2 = 0; ks2 < 8; ++ks2) {
        const half8 bf = *(const half8*)&hidf[FOFF((ks2 * 4 + w) * 64 + lane)];
#pragma unroll
        for (int rt = 0; rt < 5; ++rt) {
            const half8 af = *(const half8*)(w2s + ((size_t)(rt * 8 + ks2) * 64 + lane) * 8);
            c2[rt] = __builtin_amdgcn_mfma_f32_16x16x32_f16(af, bf, c2[rt], 0, 0, 0);
        }
    }
    __syncthreads();   // all hidf reads done; alias LDS as x2t/prop

    // ---- write x2 tile to LDS only (x2 never goes to HBM) ----
    const int pxl = w * 16 + m16;
#pragma unroll
    for (int rt = 0; rt < 5; ++rt) {
#pragma unroll
        for (int r = 0; r < 4; ++r) {
            const int o2 = rt * 16 + kgr * 4 + r;
            if (o2 < OC) x2t[pxl * 69 + o2] = c2[rt][r] + b2[o2];
        }
    }
    __syncthreads();

    // ---- build 576 proposals (a, px) into LDS ----
    for (int pi = t; pi < A_ * 64; pi += 256) {
        const int a  = pi >> 6;
        const int px = pi & 63;
        const float* xr = x2t + px * 69 + 5 * a;
        const float tx = xr[1], ty = xr[2], tw = xr[3], th = xr[4];
        const int hw = p0 + px;
        const int h  = hw / W_;
        const int wv = hw - h * W_;
        const float gx = (float)wv + 0.5f;
        const float gy = (float)h + 0.5f;
        const float nw = anc[2 * a]     * __expf(tw);
        const float nh = anc[2 * a + 1] * __expf(th);
        const float cx = gx + tx, cy = gy + ty;
        ppx1[pi] = cx - 0.5f * nw; ppy1[pi] = cy - 0.5f * nh;
        ppx2[pi] = cx + 0.5f * nw; ppy2[pi] = cy + 0.5f * nh;
        pare[pi] = nw * nh;
    }
    __syncthreads();

    // ---- IoU stream-out: per (a,q) each wave stores one contiguous 1KB span ----
    const int pr = lane >> 4;
    const int j0 = (lane & 15) * 4;
    float Bx1[4], By1[4], Bx2[4], By2[4], Ba[4];
#pragma unroll
    for (int e = 0; e < 4; ++e) {
        Bx1[e] = boxs[j0 + e];       By1[e] = boxs[64 + j0 + e];
        Bx2[e] = boxs[128 + j0 + e]; By2[e] = boxs[192 + j0 + e];
        Ba[e]  = boxs[256 + j0 + e];
    }
    float* ibase = iou_out + ((size_t)b * AHW + p0) * 64;
#pragma unroll 1
    for (int a = 0; a < A_; ++a) {
#pragma unroll
        for (int q = 0; q < 4; ++q) {
            const int p = w * 16 + q * 4 + pr;
            const int i = a * 64 + p;
            const float Px1 = ppx1[i], Py1 = ppy1[i], Px2 = ppx2[i], Py2 = ppy2[i];
            const float pa = pare[i];
            f32x4 o4;
#pragma unroll
            for (int e = 0; e < 4; ++e) {
                const float iw = fminf(Px2, Bx2[e]) - fmaxf(Px1, Bx1[e]);
                const float ih = fminf(Py2, By2[e]) - fmaxf(Py1, By1[e]);
                const float inter = fmaxf(iw, 0.f) * fmaxf(ih, 0.f);
                o4[e] = inter * __builtin_amdgcn_rcpf(Ba[e] + pa - inter);
            }
            __builtin_nontemporal_store(o4, (f32x4*)(ibase + ((size_t)a * HW + p) * 64 + j0));
        }
    }

    // ---- pos/neg index scans: class rows + loss partials from LDS tile ----
    float csum = 0.f, rsum = 0.f;
    for (int m = t; m < M_; m += 256) {
        const int idx = pos_idx[m];
        const int bi  = idx / AHW;
        const int rr  = idx - bi * AHW;
        const int a   = rr / HW;
        const int px  = (rr - a * HW) - p0;
        if (bi == b && px >= 0 && px < 64) {
            const float* xr = x2t + px * 69;
            const float s = 1.f / (1.f + __expf(-xr[5 * a]));
            csum += (s - 1.f) * (s - 1.f);
#pragma unroll
            for (int k = 0; k < 4; ++k) {
                const float d = xr[5 * a + 1 + k] - gt_off[m * 4 + k];
                rsum += d * d;
            }
            float* co = cls_out + (size_t)m * CNUM;
#pragma unroll
            for (int c = 0; c < CNUM; ++c) co[c] = xr[45 + c];
        }
    }
    for (int m = t; m < M_; m += 256) {
        const int idx = neg_idx[m];
        const int bi  = idx / AHW;
        const int rr  = idx - bi * AHW;
        const int a   = rr / HW;
        const int px  = (rr - a * HW) - p0;
        if (bi == b && px >= 0 && px < 64) {
            const float s = 1.f / (1.f + __expf(-x2t[px * 69 + 5 * a]));
            csum += s * s;
        }
    }
#pragma unroll
    for (int off = 32; off > 0; off >>= 1) {
        csum += __shfl_down(csum, off, 64);
        rsum += __shfl_down(rsum, off, 64);
    }
    if (lane == 0) { red[w] = csum; red[4 + w] = rsum; }
    __syncthreads();
    if (t == 0) {
        const float c  = red[0] + red[1] + red[2] + red[3];
        const float rg = red[4] + red[5] + red[6] + red[7];
        if (c != 0.f || rg != 0.f) {
            atomicAdd(&loss_ws[0], c);
            atomicAdd(&loss_ws[1], rg);
        }
    }
}

__global__ void finalize_kernel(const float* __restrict__ loss_ws, float* __restrict__ out0)
{
    out0[0] = loss_ws[0] / (2.f * (float)M_) + loss_ws[1] / (float)M_;
}

extern "C" void kernel_launch(void* const* d_in, const int* in_sizes, int n_in,
                              void* d_out, int out_size, void* d_ws, size_t ws_size,
                              hipStream_t stream) {
    (void)in_sizes; (void)n_in; (void)out_size; (void)ws_size;
    const float* features = (const float*)d_in[0];
    const float* w1       = (const float*)d_in[1];
    const float* b1       = (const float*)d_in[2];
    const float* w2       = (const float*)d_in[3];
    const float* b2       = (const float*)d_in[4];
    const float* anc      = (const float*)d_in[5];
    const float* bboxes   = (const float*)d_in[7];
    const float* gt_off   = (const float*)d_in[8];
    const int*   pos_idx  = (const int*)d_in[9];
    const int*   neg_idx  = (const int*)d_in[10];
    float* out = (float*)d_out;

    char* wsb = (char*)d_ws;
    _Float16* w1s  = (_Float16*)wsb;                 // 131,072 B
    _Float16* w2s  = w1s + 65536;                    // 40,960 B
    float* loss_ws = (float*)(wsb + 131072 + 40960); // 8 B

    prep_kernel<<<256, 256, 0, stream>>>(w1, w2, w1s, w2s, loss_ws);
    conv_iou_kernel<<<B_ * NTILE, 256, 0, stream>>>(features, w1s, b1, w2s, b2,
                                                    anc, bboxes, pos_idx, neg_idx,
                                                    gt_off, out + 1,
                                                    out + 1 + IOU_N, loss_ws);
    finalize_kernel<<<1, 1, 0, stream>>>(loss_ws, out);
}